// Round 16
// baseline (429.975 us; speedup 1.0000x reference)
//
#include <hip/hip_runtime.h>
#include <hip/hip_bf16.h>
#include <math.h>

#define DIN 128
#define DH  128
#define DC  40

#define HCHUNK  6272           // u32 words per LDS chunk (2 nodes/word) -> 12544 nodes
#define NCHUNK  4
#define NSTRIPE 128
#define NPAD    (HCHUNK * 2 * NCHUNK)   // 50176 padded node slots

typedef unsigned short u16;
typedef unsigned int u32;
typedef unsigned char u8;
typedef __attribute__((ext_vector_type(2))) float f32x2;
typedef __attribute__((ext_vector_type(4))) float f32x4;
typedef __attribute__((ext_vector_type(8))) short bf16x8;

static __device__ __forceinline__ float bf2f(u16 u) {
    union { u32 i; float f; } v; v.i = ((u32)u) << 16; return v.f;
}
static __device__ __forceinline__ u16 f2bf(float f) {
    __hip_bfloat16 h = __float2bfloat16(f);
    union { __hip_bfloat16 h; u16 u; } v; v.h = h; return v.u;
}
static __device__ __forceinline__ u32 pack2bf(float a, float b) {
    return ((u32)f2bf(b) << 16) | (u32)f2bf(a);
}

// ---------- fp8 e4m3fn helpers ----------
static __device__ __forceinline__ u8 f2fp8(float f) {
    u32 s = (__float_as_uint(f) >> 31) << 7;
    float a = fabsf(f);
    a = fminf(a, 448.f);
    if (a < 0.015625f) {
        int q = (int)rintf(a * 512.f);
        return (u8)(s | (u32)q);
    }
    u32 x = __float_as_uint(a);
    u32 lsb = (x >> 20) & 1;
    x += 0x0007FFFF + lsb;
    u32 e = (x >> 23) - 120;
    u32 m = (x >> 20) & 7;
    return (u8)(s | (e << 3) | m);
}

#if __has_builtin(__builtin_amdgcn_cvt_pk_f32_fp8)
template<bool HI>
static __device__ __forceinline__ f32x2 fp8pk(u32 w) {
    return __builtin_amdgcn_cvt_pk_f32_fp8((int)w, HI);
}
#else
static __device__ __forceinline__ float fp8dec1(u32 byte) {
    u32 s = (byte >> 7) & 1, em = byte & 0x7F;
    float v = __uint_as_float((s << 31) | (em << 20)) * 0x1p120f;
    return v;
}
template<bool HI>
static __device__ __forceinline__ f32x2 fp8pk(u32 w) {
    u32 b0 = HI ? ((w >> 16) & 0xff) : (w & 0xff);
    u32 b1 = HI ? ((w >> 24) & 0xff) : ((w >> 8) & 0xff);
    f32x2 r; r.x = fp8dec1(b0); r.y = fp8dec1(b1); return r;
}
#endif

// ---------- fused weight prep: w1 frags + w2 frags + attn dots + biases ----------
__global__ __launch_bounds__(256) void k_prep(
        const float* w11s, const float* w11n, const float* w12, const float* w13,
        const float* b11, const float* b12, const float* b13, const float* cw1,
        const float* w21s, const float* w21n, const float* w22, const float* w23,
        const float* b21, const float* b22, const float* b23, const float* cw2,
        const float* a13l, const float* a13r, const float* a23l, const float* a23r,
        u16* __restrict__ Wf1, u16* __restrict__ Wf2,
        float* __restrict__ bc1, float* __restrict__ bc2, float* __restrict__ vattn) {
    int i = blockIdx.x * 256 + threadIdx.x;
    float s1 = cw1[0] + cw1[1] + cw1[2];
    float u0 = cw1[0] / s1, u1 = cw1[1] / s1, u2 = cw1[2] / s1;
    float s2 = cw2[0] + cw2[1] + cw2[2];
    float q0 = cw2[0] / s2, q1 = cw2[1] / s2, q2 = cw2[2] / s2;
    if (i < 65536) {                                   // Wf1 frags
        int j = i & 7, lane = (i >> 3) & 63, nt = (i >> 9) & 7, kt = i >> 12;
        int k = kt * 32 + ((lane >> 4) << 3) + j;
        int n = nt * 16 + (lane & 15);
        float v;
        if (k < 128)      v = u0 * w11s[k * 128 + n];
        else if (k < 256) v = u0 * w11n[(k - 128) * 128 + n];
        else if (k < 384) v = u1 * w12[(k - 256) * 128 + n];
        else              v = u2 * w13[(k - 384) * 128 + n];
        Wf1[i] = f2bf(v);
    } else if (i < 90112) {                            // Wf2 frags
        int i2 = i - 65536;
        int j = i2 & 7;
        int l2 = i2 >> 3;
        int lane = l2 & 63;
        int t2 = l2 >> 6;
        int nt = t2 % 3, kt = t2 / 3;
        int k = kt * 32 + ((lane >> 4) << 3) + j;
        int n = nt * 16 + (lane & 15);
        float v = 0.f;
        if (n < 40) {
            if (k < 128)      v = q0 * w21s[k * 40 + n];
            else if (k < 256) v = q0 * w21n[(k - 128) * 40 + n];
            else if (k < 384) v = q1 * w22[(k - 256) * 40 + n];
            else              v = q2 * w23[(k - 384) * 40 + n];
        }
        Wf2[i2] = f2bf(v);
    } else if (i < 90624) {                            // attn dots
        int t = i - 90112;
        if (t < 128) {
            float s = 0; for (int j = 0; j < 128; ++j) s += w13[t * 128 + j] * a13l[j];
            vattn[t] = s;
        } else if (t < 256) {
            int r = t - 128; float s = 0; for (int j = 0; j < 128; ++j) s += w13[r * 128 + j] * a13r[j];
            vattn[t] = s;
        } else if (t < 384) {
            int r = t - 256; float s = 0; for (int j = 0; j < 40; ++j) s += w23[r * 40 + j] * a23l[j];
            vattn[t] = s;
        } else {
            int r = t - 384; float s = 0; for (int j = 0; j < 40; ++j) s += w23[r * 40 + j] * a23r[j];
            vattn[t] = s;
        }
    } else if (i < 90752) {                            // bc1
        int c = i - 90624;
        bc1[c] = u0 * b11[c] + u1 * b12[c] + u2 * b13[c];
    } else if (i < 90792) {                            // bc2
        int c = i - 90752;
        bc2[c] = q0 * b21[c] + q1 * b22[c] + q2 * b23[c];
    }
}

// ---------- CSR build: dual LDS histogram (src + dst), 4 node-chunks x 50KB ----------
__global__ __launch_bounds__(256) void k_hist2(const int* __restrict__ src,
        const int* __restrict__ dst,
        u16* __restrict__ partialsS, u16* __restrict__ partialsD,
        u16* __restrict__ wsrank, int E, int eps) {
    __shared__ u32 histS[HCHUNK];
    __shared__ u32 histD[HCHUNK];
    int chunk = blockIdx.x;
    int stripe = blockIdx.y;
    int base = chunk * (HCHUNK * 2);
    for (int i = threadIdx.x; i < HCHUNK; i += 256) { histS[i] = 0; histD[i] = 0; }
    __syncthreads();
    int e0 = stripe * eps;
    int e1 = e0 + eps; if (e1 > E) e1 = E;
    for (int e = e0 + threadIdx.x; e < e1; e += 256) {
        int ks = src[e] - base;
        int kd = dst[e] - base;
        if ((u32)ks < (u32)(HCHUNK * 2))
            atomicAdd(&histS[ks >> 1], 1u << ((ks & 1) * 16));
        if ((u32)kd < (u32)(HCHUNK * 2)) {
            u32 old = atomicAdd(&histD[kd >> 1], 1u << ((kd & 1) * 16));
            wsrank[e] = (u16)((old >> ((kd & 1) * 16)) & 0xffff);
        }
    }
    __syncthreads();
    u32* prowS = (u32*)(partialsS + (size_t)stripe * NPAD + base);
    u32* prowD = (u32*)(partialsD + (size_t)stripe * NPAD + base);
    for (int i = threadIdx.x; i < HCHUNK; i += 256) { prowS[i] = histS[i]; prowD[i] = histD[i]; }
}

// per-node: src totals -> ns; dst prefix in place -> indeg; FUSED block scan (scan1)
__global__ __launch_bounds__(256) void k_pfx2(const u16* __restrict__ partialsS,
        u16* __restrict__ partialsD, int* __restrict__ excl, int* __restrict__ bsum,
        float* __restrict__ ns, int n) {
    __shared__ int sh[256];
    int node = blockIdx.x * 256 + threadIdx.x;
    int runS = 0, runD = 0;
    if (node < NPAD) {
        for (int s0 = 0; s0 < NSTRIPE; s0 += 16) {
            u16 c[16];
#pragma unroll
            for (int i = 0; i < 16; ++i) c[i] = partialsS[(size_t)(s0 + i) * NPAD + node];
#pragma unroll
            for (int i = 0; i < 16; ++i) runS += c[i];
        }
        for (int s0 = 0; s0 < NSTRIPE; s0 += 16) {
            u16 c[16];
#pragma unroll
            for (int i = 0; i < 16; ++i) c[i] = partialsD[(size_t)(s0 + i) * NPAD + node];
#pragma unroll
            for (int i = 0; i < 16; ++i) {
                partialsD[(size_t)(s0 + i) * NPAD + node] = (u16)runD;
                runD += c[i];
            }
        }
        if (node < n) {
            int d = runS < 1 ? 1 : runS;
            ns[node] = rsqrtf((float)d);
        }
    }
    int v = (node < n) ? runD : 0;
    sh[threadIdx.x] = v; __syncthreads();
    for (int o = 1; o < 256; o <<= 1) {
        int t = (threadIdx.x >= o) ? sh[threadIdx.x - o] : 0;
        __syncthreads(); sh[threadIdx.x] += t; __syncthreads();
    }
    if (node < NPAD) excl[node] = sh[threadIdx.x] - v;
    if (threadIdx.x == 255) bsum[blockIdx.x] = sh[255];
}

// merged scan2+scan3: each block scans bsum in LDS, then writes rowptr
__global__ __launch_bounds__(256) void k_scan23(const int* __restrict__ excl,
        const int* __restrict__ bsum, int* __restrict__ rowptr, int nb, int n, int E) {
    __shared__ int sh[256];
    int t = threadIdx.x;
    int v = (t < nb) ? bsum[t] : 0;
    sh[t] = v; __syncthreads();
    for (int o = 1; o < 256; o <<= 1) {
        int u = (t >= o) ? sh[t - o] : 0;
        __syncthreads(); sh[t] += u; __syncthreads();
    }
    int bpre = sh[blockIdx.x] - bsum[blockIdx.x];   // exclusive prefix for this block
    __syncthreads();
    int i = blockIdx.x * 256 + t;
    if (i < n) rowptr[i] = excl[i] + bpre;
    if (i == 0) rowptr[n] = E;
}

// atomic-free placement: rowptr + stripe-prefix + within-stripe rank
__global__ __launch_bounds__(256) void k_place2(const int* __restrict__ src,
        const int* __restrict__ dst, const int* __restrict__ rowptr,
        const u16* __restrict__ partials, const u16* __restrict__ wsrank,
        int* __restrict__ col, int E, int eps) {
    int stripe = blockIdx.x;
    const u16* prow = partials + (size_t)stripe * NPAD;
    int sub = (eps + 3) >> 2;
    int e0 = stripe * eps + blockIdx.y * sub;
    int e1 = e0 + sub;
    int cap = stripe * eps + eps; if (cap > E) cap = E;
    if (e1 > cap) e1 = cap;
    for (int e = e0 + threadIdx.x; e < e1; e += 256) {
        int d = dst[e];
        col[rowptr[d] + prow[d] + wsrank[e]] = src[e];
    }
}

// ---------- fused: f32 x -> bf16 Xb + fp8 Xq + logits (elns packed) ----------
__global__ __launch_bounds__(256) void k_cvt_dots(const float* __restrict__ X,
        const float* __restrict__ vl, const float* __restrict__ vr, const float* __restrict__ ns,
        u16* __restrict__ Xb, u8* __restrict__ Xq,
        float2* __restrict__ elns, float* __restrict__ er, int n) {
    int w = (blockIdx.x * blockDim.x + threadIdx.x) >> 6;
    int lane = threadIdx.x & 63;
    if (w >= n) return;
    float2 xv = *(const float2*)&X[(size_t)w * 128 + lane * 2];
    *(u32*)&Xb[(size_t)w * 128 + lane * 2] = pack2bf(xv.x, xv.y);
    u16 q = (u16)f2fp8(xv.x) | ((u16)f2fp8(xv.y) << 8);
    *(u16*)&Xq[(size_t)w * 128 + lane * 2] = q;
    float2 a = *(const float2*)&vl[lane * 2];
    float2 b = *(const float2*)&vr[lane * 2];
    float dl = xv.x * a.x + xv.y * a.y;
    float dr = xv.x * b.x + xv.y * b.y;
    for (int off = 32; off; off >>= 1) {
        dl += __shfl_down(dl, off);
        dr += __shfl_down(dr, off);
    }
    if (lane == 0) { elns[w] = make_float2(dl, ns[w]); er[w] = dr; }
}

// ---------- aggregation: interleaved 4 edges/step; softmax without online max ----------
__global__ __launch_bounds__(256) void k_agg(const u8* __restrict__ Xq,
        const int* __restrict__ rowptr, const int* __restrict__ colsrc,
        const float2* __restrict__ elns, const float* __restrict__ er,
        u16* __restrict__ AG, int n) {
    int w = (blockIdx.x * blockDim.x + threadIdx.x) >> 6;
    int lane = threadIdx.x & 63;
    if (w >= n) return;
    int g = lane >> 4, gl = lane & 15;
    int beg = rowptr[w], end = rowptr[w + 1];
    int k = end - beg;
    float erd = er[w];
    f32x2 aS2[4] = {}, aG2[4] = {}, aA2[4] = {};
    float ssum = 0.f;
    for (int c0 = beg; c0 < end; c0 += 64) {
        int cnt = end - c0; if (cnt > 64) cnt = 64;
        int s = 0; float p = 0.f; float nsl = 0.f;
        if (lane < cnt) {
            s = colsrc[c0 + lane];
            float2 v = elns[s];
            float t = v.x + erd;
            t = t > 0.f ? t : 0.2f * t;            // leaky_relu 0.2
            p = __expf(t);
            nsl = v.y;
        }
        float ps = p;
        for (int o = 32; o; o >>= 1) ps += __shfl_xor(ps, o);
        ssum += ps;
        int full = cnt >> 2;                       // guard-free steps
#pragma unroll 8
        for (int t = 0; t < full; ++t) {
            int j = (t << 2) + g;                  // j < cnt guaranteed
            int sj = __shfl(s, j);
            float pj = __shfl(p, j);
            float nsj = __shfl(nsl, j);
            uint2 xq = *(const uint2*)&Xq[(size_t)sj * 128 + gl * 8];
            f32x2 xv2[4] = {fp8pk<false>(xq.x), fp8pk<true>(xq.x),
                            fp8pk<false>(xq.y), fp8pk<true>(xq.y)};
            f32x2 ns2 = {nsj, nsj}, p2 = {pj, pj};
#pragma unroll
            for (int q = 0; q < 4; ++q) {
                aS2[q] += xv2[q];
                aG2[q] += ns2 * xv2[q];
                aA2[q] += p2 * xv2[q];
            }
        }
        if (cnt & 3) {                             // tail step (guarded)
            int j = (full << 2) + g;
            int sj = __shfl(s, j);
            float pj = __shfl(p, j);
            float nsj = __shfl(nsl, j);
            if (j < cnt) {
                uint2 xq = *(const uint2*)&Xq[(size_t)sj * 128 + gl * 8];
                f32x2 xv2[4] = {fp8pk<false>(xq.x), fp8pk<true>(xq.x),
                                fp8pk<false>(xq.y), fp8pk<true>(xq.y)};
                f32x2 ns2 = {nsj, nsj}, p2 = {pj, pj};
#pragma unroll
                for (int q = 0; q < 4; ++q) {
                    aS2[q] += xv2[q];
                    aG2[q] += ns2 * xv2[q];
                    aA2[q] += p2 * xv2[q];
                }
            }
        }
    }
    float aS[8], aG[8], aA[8];
#pragma unroll
    for (int i = 0; i < 4; ++i) {
        aS[2 * i] = aS2[i][0]; aS[2 * i + 1] = aS2[i][1];
        aG[2 * i] = aG2[i][0]; aG[2 * i + 1] = aG2[i][1];
        aA[2 * i] = aA2[i][0]; aA[2 * i + 1] = aA2[i][1];
    }
#pragma unroll
    for (int i = 0; i < 8; ++i) {
        aS[i] += __shfl_xor(aS[i], 16); aS[i] += __shfl_xor(aS[i], 32);
        aG[i] += __shfl_xor(aG[i], 16); aG[i] += __shfl_xor(aG[i], 32);
        aA[i] += __shfl_xor(aA[i], 16); aA[i] += __shfl_xor(aA[i], 32);
    }
    int kc = k < 1 ? 1 : k;
    float invk = 1.f / (float)kc;
    float ndd = rsqrtf((float)kc);
    float gi = 1.f / fmaxf(ssum, 1e-9f);
    u16* row = AG + (size_t)w * 384;
    if (g == 0) {
        uint4 o = make_uint4(pack2bf(aS[0] * invk, aS[1] * invk), pack2bf(aS[2] * invk, aS[3] * invk),
                             pack2bf(aS[4] * invk, aS[5] * invk), pack2bf(aS[6] * invk, aS[7] * invk));
        *(uint4*)&row[gl * 8] = o;
    } else if (g == 1) {
        uint4 o = make_uint4(pack2bf(aG[0] * ndd, aG[1] * ndd), pack2bf(aG[2] * ndd, aG[3] * ndd),
                             pack2bf(aG[4] * ndd, aG[5] * ndd), pack2bf(aG[6] * ndd, aG[7] * ndd));
        *(uint4*)&row[128 + gl * 8] = o;
    } else if (g == 2) {
        uint4 o = make_uint4(pack2bf(aA[0] * gi, aA[1] * gi), pack2bf(aA[2] * gi, aA[3] * gi),
                             pack2bf(aA[4] * gi, aA[5] * gi), pack2bf(aA[6] * gi, aA[7] * gi));
        *(uint4*)&row[256 + gl * 8] = o;
    }
}

// ---------- MFMA GEMM layer1: C(Mx128 bf16) = [Xb|AG] @ Wf + bias; zeroes bnacc ----------
__global__ __launch_bounds__(256) void k_gemm1(const u16* __restrict__ Xb,
        const u16* __restrict__ AG, const u16* __restrict__ Wf,
        const float* __restrict__ bias, u16* __restrict__ C,
        float* __restrict__ bnacc, int M) {
    if (blockIdx.x == 0 && threadIdx.x < 256) bnacc[threadIdx.x] = 0.f;
    const int NT = 8;
    int wave = threadIdx.x >> 6;
    int lane = threadIdx.x & 63;
    int m0 = blockIdx.x * 64 + wave * 16;
    int arow = m0 + (lane & 15);
    if (arow >= M) arow = M - 1;
    int kq = lane >> 4;
    f32x4 acc[NT];
#pragma unroll
    for (int t = 0; t < NT; ++t) acc[t] = (f32x4){0.f, 0.f, 0.f, 0.f};
#pragma unroll
    for (int kt = 0; kt < 16; ++kt) {
        int k0 = kt * 32 + kq * 8;
        bf16x8 a;
        if (k0 < 128) a = *(const bf16x8*)&Xb[(size_t)arow * 128 + k0];
        else          a = *(const bf16x8*)&AG[(size_t)arow * 384 + (k0 - 128)];
        const u16* wb = Wf + ((size_t)kt * NT) * 512 + lane * 8;
#pragma unroll
        for (int t = 0; t < NT; ++t) {
            bf16x8 b = *(const bf16x8*)&wb[(size_t)t * 512];
            acc[t] = __builtin_amdgcn_mfma_f32_16x16x32_bf16(a, b, acc[t], 0, 0, 0);
        }
    }
    int ccol = lane & 15;
    int rbase = m0 + kq * 4;
#pragma unroll
    for (int t = 0; t < NT; ++t) {
        int col = t * 16 + ccol;
        float bv = bias[col];
#pragma unroll
        for (int r = 0; r < 4; ++r) {
            int rr = rbase + r;
            if (rr < M) C[(size_t)rr * 128 + col] = f2bf(acc[t][r] + bv);
        }
    }
}

// ---------- MFMA GEMM layer2 (N=40) fused with log_softmax, writes f32 out ----------
__global__ __launch_bounds__(256) void k_gemm2_lsm(const u16* __restrict__ Xb,
        const u16* __restrict__ AG, const u16* __restrict__ Wf,
        const float* __restrict__ bias, float* __restrict__ out, int M) {
    const int NT = 3;
    int wave = threadIdx.x >> 6;
    int lane = threadIdx.x & 63;
    int m0 = blockIdx.x * 64 + wave * 16;
    int arow = m0 + (lane & 15);
    if (arow >= M) arow = M - 1;
    int kq = lane >> 4;
    f32x4 acc[NT];
#pragma unroll
    for (int t = 0; t < NT; ++t) acc[t] = (f32x4){0.f, 0.f, 0.f, 0.f};
#pragma unroll
    for (int kt = 0; kt < 16; ++kt) {
        int k0 = kt * 32 + kq * 8;
        bf16x8 a;
        if (k0 < 128) a = *(const bf16x8*)&Xb[(size_t)arow * 128 + k0];
        else          a = *(const bf16x8*)&AG[(size_t)arow * 384 + (k0 - 128)];
        const u16* wb = Wf + ((size_t)kt * NT) * 512 + lane * 8;
#pragma unroll
        for (int t = 0; t < NT; ++t) {
            bf16x8 b = *(const bf16x8*)&wb[(size_t)t * 512];
            acc[t] = __builtin_amdgcn_mfma_f32_16x16x32_bf16(a, b, acc[t], 0, 0, 0);
        }
    }
    int ccol = lane & 15;
    int rbase = m0 + kq * 4;
    bool valid[NT];
    float bv[NT];
#pragma unroll
    for (int t = 0; t < NT; ++t) {
        int col = t * 16 + ccol;
        valid[t] = (col < 40);
        bv[t] = valid[t] ? bias[col] : 0.f;
    }
#pragma unroll
    for (int r = 0; r < 4; ++r) {
        float v[NT];
#pragma unroll
        for (int t = 0; t < NT; ++t) v[t] = valid[t] ? (acc[t][r] + bv[t]) : -INFINITY;
        float mx = fmaxf(fmaxf(v[0], v[1]), v[2]);
        for (int o = 1; o < 16; o <<= 1) mx = fmaxf(mx, __shfl_xor(mx, o));
        float se = 0.f;
#pragma unroll
        for (int t = 0; t < NT; ++t) se += valid[t] ? __expf(v[t] - mx) : 0.f;
        for (int o = 1; o < 16; o <<= 1) se += __shfl_xor(se, o);
        float lse = mx + logf(se);
        int rr = rbase + r;
        if (rr < M) {
#pragma unroll
            for (int t = 0; t < NT; ++t) {
                int col = t * 16 + ccol;
                if (valid[t]) out[(size_t)rr * 40 + col] = v[t] - lse;
            }
        }
    }
}

// ---------- BatchNorm stats (hpre bf16) ----------
__global__ __launch_bounds__(256) void k_bn_stats(const u16* __restrict__ H,
        float* __restrict__ acc, int nrows) {
    int c = threadIdx.x & 127;
    int rh = threadIdx.x >> 7;
    int r0 = blockIdx.x * 256;
    int rend = r0 + 256; if (rend > nrows) rend = nrows;
    float s = 0.f, q = 0.f;
    for (int r = r0 + rh; r < rend; r += 2) {
        float v = bf2f(H[(size_t)r * 128 + c]);
        s += v; q += v * v;
    }
    atomicAdd(&acc[c], s);
    atomicAdd(&acc[128 + c], q);
}

// ---------- fused: BN-final + BN+ReLU -> bf16 h + fp8 h8 + layer-2 logits ----------
__global__ __launch_bounds__(256) void k_bnorm_dots(const u16* __restrict__ Hp,
        const float* __restrict__ bnacc, const float* __restrict__ g, const float* __restrict__ be,
        const float* __restrict__ vl, const float* __restrict__ vr,
        const float* __restrict__ ns,
        u16* __restrict__ H, u8* __restrict__ H8,
        float2* __restrict__ elns, float* __restrict__ er, float Nf, int n) {
    int w = (blockIdx.x * blockDim.x + threadIdx.x) >> 6;
    int lane = threadIdx.x & 63;
    if (w >= n) return;
    int c0 = lane * 2, c1 = lane * 2 + 1;
    float mu0 = bnacc[c0] / Nf, mu1 = bnacc[c1] / Nf;
    float var0 = bnacc[128 + c0] / Nf - mu0 * mu0;
    float var1 = bnacc[128 + c1] / Nf - mu1 * mu1;
    float sc0 = g[c0] * rsqrtf(var0 + 1e-5f);
    float sc1 = g[c1] * rsqrtf(var1 + 1e-5f);
    float sh0 = be[c0] - mu0 * sc0;
    float sh1 = be[c1] - mu1 * sc1;
    u32 hu = *(const u32*)&Hp[(size_t)w * 128 + lane * 2];
    float vx = bf2f((u16)hu), vy = bf2f((u16)(hu >> 16));
    float h0 = fmaxf(vx * sc0 + sh0, 0.f);
    float h1 = fmaxf(vy * sc1 + sh1, 0.f);
    *(u32*)&H[(size_t)w * 128 + lane * 2] = pack2bf(h0, h1);
    u16 q = (u16)f2fp8(h0) | ((u16)f2fp8(h1) << 8);
    *(u16*)&H8[(size_t)w * 128 + lane * 2] = q;
    float2 a = *(const float2*)&vl[lane * 2];
    float2 b = *(const float2*)&vr[lane * 2];
    float dl = h0 * a.x + h1 * a.y;
    float dr = h0 * b.x + h1 * b.y;
    for (int off = 32; off; off >>= 1) {
        dl += __shfl_down(dl, off);
        dr += __shfl_down(dr, off);
    }
    if (lane == 0) { elns[w] = make_float2(dl, ns[w]); er[w] = dr; }
}

extern "C" void kernel_launch(void* const* d_in, const int* in_sizes, int n_in,
                              void* d_out, int out_size, void* d_ws, size_t ws_size,
                              hipStream_t stream) {
    const float* x    = (const float*)d_in[0];
    const int*   src  = (const int*)d_in[1];
    const int*   dst  = (const int*)d_in[2];
    const float* w11s = (const float*)d_in[3];
    const float* w11n = (const float*)d_in[4];
    const float* b11  = (const float*)d_in[5];
    const float* w12  = (const float*)d_in[6];
    const float* b12  = (const float*)d_in[7];
    const float* w13  = (const float*)d_in[8];
    const float* a13l = (const float*)d_in[9];
    const float* a13r = (const float*)d_in[10];
    const float* b13  = (const float*)d_in[11];
    const float* cw1  = (const float*)d_in[12];
    const float* g    = (const float*)d_in[13];
    const float* be   = (const float*)d_in[14];
    const float* w21s = (const float*)d_in[15];
    const float* w21n = (const float*)d_in[16];
    const float* b21  = (const float*)d_in[17];
    const float* w22  = (const float*)d_in[18];
    const float* b22  = (const float*)d_in[19];
    const float* w23  = (const float*)d_in[20];
    const float* a23l = (const float*)d_in[21];
    const float* a23r = (const float*)d_in[22];
    const float* b23  = (const float*)d_in[23];
    const float* cw2  = (const float*)d_in[24];

    const int N = in_sizes[0] / DIN;
    const int E = in_sizes[1];

    char* ws = (char*)d_ws;
    size_t off = 0;
    auto alloc = [&](size_t bytes) { size_t o = off; off += (bytes + 255) & ~(size_t)255; return o; };
    u16*   Xb     = (u16*)(ws + alloc((size_t)N * 128 * 2));
    u8*    Xq     = (u8*)(ws + alloc((size_t)N * 128));
    u16*   AG     = (u16*)(ws + alloc((size_t)N * 384 * 2));
    u16*   hpre   = (u16*)(ws + alloc((size_t)N * 128 * 2));
    u16*   h      = (u16*)(ws + alloc((size_t)N * 128 * 2));
    u8*    h8     = (u8*)(ws + alloc((size_t)N * 128));
    int*   col    = (int*)(ws + alloc((size_t)E * 4));
    u16*   wsrank = (u16*)(ws + alloc((size_t)E * 2));
    u16*   partialsS = (u16*)(ws + alloc((size_t)NSTRIPE * NPAD * 2));
    u16*   partialsD = (u16*)(ws + alloc((size_t)NSTRIPE * NPAD * 2));
    int*   rowptr = (int*)(ws + alloc((size_t)(N + 1) * 4));
    int*   excl   = (int*)(ws + alloc((size_t)NPAD * 4));
    int*   bsum   = (int*)(ws + alloc(256 * 4));
    float* ns     = (float*)(ws + alloc((size_t)N * 4));
    float2* elns  = (float2*)(ws + alloc((size_t)N * 8));
    float* er     = (float*)(ws + alloc((size_t)N * 4));
    u16*   Wf1    = (u16*)(ws + alloc((size_t)16 * 8 * 64 * 8 * 2));
    u16*   Wf2    = (u16*)(ws + alloc((size_t)16 * 3 * 64 * 8 * 2));
    float* bc1    = (float*)(ws + alloc(128 * 4));
    float* bc2    = (float*)(ws + alloc(40 * 4));
    float* vattn  = (float*)(ws + alloc(512 * 4));
    float* bnacc  = (float*)(ws + alloc(256 * 4));

    int eb_eps = (E + NSTRIPE - 1) / NSTRIPE;
    int wb = (N * 64 + 255) / 256;
    int gb = (N + 63) / 64;
    int pb = (NPAD + 255) / 256;   // 196 blocks

    // fused weight prep (Wf1 + Wf2 + attn + biases)
    k_prep<<<(90792 + 255) / 256, 256, 0, stream>>>(
        w11s, w11n, w12, w13, b11, b12, b13, cw1,
        w21s, w21n, w22, w23, b21, b22, b23, cw2,
        a13l, a13r, a23l, a23r, Wf1, Wf2, bc1, bc2, vattn);

    // CSR build: dual histogram (4 chunks x 50KB LDS), fused prefix+scan, place
    {
        dim3 hg(NCHUNK, NSTRIPE);
        k_hist2<<<hg, 256, 0, stream>>>(src, dst, partialsS, partialsD, wsrank, E, eb_eps);
        k_pfx2<<<pb, 256, 0, stream>>>(partialsS, partialsD, excl, bsum, ns, N);
        k_scan23<<<pb, 256, 0, stream>>>(excl, bsum, rowptr, pb, N, E);
        dim3 pg(NSTRIPE, 4);
        k_place2<<<pg, 256, 0, stream>>>(src, dst, rowptr, partialsD, wsrank, col, E, eb_eps);
    }

    // ---- layer 1 ----
    k_cvt_dots<<<wb, 256, 0, stream>>>(x, vattn, vattn + 128, ns, Xb, Xq, elns, er, N);
    k_agg<<<wb, 256, 0, stream>>>(Xq, rowptr, col, elns, er, AG, N);
    k_gemm1<<<gb, 256, 0, stream>>>(Xb, AG, Wf1, bc1, hpre, bnacc, N);

    // BatchNorm stats, then fused final+norm+logits
    k_bn_stats<<<(N + 255) / 256, 256, 0, stream>>>(hpre, bnacc, N);
    k_bnorm_dots<<<wb, 256, 0, stream>>>(hpre, bnacc, g, be, vattn + 256, vattn + 384, ns,
                                         h, h8, elns, er, (float)N, N);

    // ---- layer 2 ----
    k_agg<<<wb, 256, 0, stream>>>(h8, rowptr, col, elns, er, AG, N);
    k_gemm2_lsm<<<gb, 256, 0, stream>>>(h, AG, Wf2, bc2, (float*)d_out, N);
}